// Round 5
// baseline (132.268 us; speedup 1.0000x reference)
//
#include <hip/hip_runtime.h>
#include <hip/hip_fp16.h>

// SDDMM: out[n] = mask_vals[n] + dot(mat1[rows[n], :], mat2[:, cols[n]])
// NNZ = 1e6, M = N = 8192, K = 128, fp32 in/out. Indices int32 per harness.
//
// R1: fp32 ws 8 MB > 4 MiB/XCD L2 -> 277 MB fabric traffic, 80 us.
// R2: fp16 (4 MB, L2-resident) -> 63 us, latency-bound (MLP=2).
// R3: batch 4 nnz/group (MLP up) -> ~42 us kernel; TA line-probe bound
//     (8 cache lines/nnz, ~3.2 cyc/line/CU).
// R4: col-slab sort + LDS slab halves lines/nnz but sort impl cost ~45 us
//     (serial base_kernel, colscan, 7 dispatches) -> regressed.
// R5: same slab sddmm; sort rebuilt: fused prep, LDS-aggregated hist ->
//     global totals, single-wave shfl scan, cursor-claim scatter writing one
//     16 B record/nnz. 5 dispatches total.

#define KDIM 128
#define NBUCK 64       // col slabs: col >> 7
#define SLAB_COLS 128  // 128 cols * 256 B = 32 KB LDS slab
#define NBLK 512       // hist/scatter blocks
#define SUBS 16        // WGs per bucket in sddmm

typedef _Float16 half2v __attribute__((ext_vector_type(2)));

union F4H8 {
  float4 f4;
  half2v h2[4];
  _Float16 h[8];
};

// ---------- K1: convert mat1 + transpose/convert mat2 + zero totals ----------

__global__ __launch_bounds__(256) void prep_kernel(
    const float* __restrict__ mat1, _Float16* __restrict__ m1h, int m1_sz,
    const float* __restrict__ mat2, _Float16* __restrict__ m2th, int N,
    int* __restrict__ tot, int nconvblk) {
  __shared__ float tile[32][33];
  int blk = blockIdx.x;
  if (blk < nconvblk) {
    if (blk == 0 && threadIdx.x < NBUCK) tot[threadIdx.x] = 0;
    int i = (blk * 256 + threadIdx.x) * 8;
    if (i < m1_sz) {
      const float4* p = (const float4*)(mat1 + i);
      float4 x0 = p[0];
      float4 x1 = p[1];
      F4H8 o;
      o.h[0] = (_Float16)x0.x; o.h[1] = (_Float16)x0.y;
      o.h[2] = (_Float16)x0.z; o.h[3] = (_Float16)x0.w;
      o.h[4] = (_Float16)x1.x; o.h[5] = (_Float16)x1.y;
      o.h[6] = (_Float16)x1.z; o.h[7] = (_Float16)x1.w;
      *(float4*)(m1h + i) = o.f4;
    }
    return;
  }
  // transpose blocks: mat2 [128, N] -> m2th [N, 128] fp16
  int u = blk - nconvblk;
  int nbx = N / 32;
  int bx = (u % nbx) * 32;  // N dim
  int by = (u / nbx) * 32;  // K dim
  int tx = threadIdx.x & 31;
  int ty = threadIdx.x >> 5;  // 0..7
#pragma unroll
  for (int j = 0; j < 32; j += 8) {
    tile[ty + j][tx] = mat2[(size_t)(by + ty + j) * N + (bx + tx)];
  }
  __syncthreads();
#pragma unroll
  for (int j = 0; j < 32; j += 8) {
    m2th[(size_t)(bx + ty + j) * KDIM + (by + tx)] = (_Float16)tile[tx][ty + j];
  }
}

// ---------- K2: histogram -> global totals (LDS-aggregated) ----------

__global__ __launch_bounds__(256) void hist_kernel(
    const int* __restrict__ cols, int nnz, int epb, int* __restrict__ tot) {
  __shared__ int h[NBUCK];
  if (threadIdx.x < NBUCK) h[threadIdx.x] = 0;
  __syncthreads();
  int lo = blockIdx.x * epb;
  int hi = min(lo + epb, nnz);
  for (int i = lo + threadIdx.x; i < hi; i += 256) {
    atomicAdd(&h[cols[i] >> 7], 1);
  }
  __syncthreads();
  if (threadIdx.x < NBUCK && h[threadIdx.x]) {
    atomicAdd(&tot[threadIdx.x], h[threadIdx.x]);
  }
}

// ---------- K3: single-wave exclusive scan of padded totals ----------

__global__ __launch_bounds__(64) void scan_kernel(
    const int* __restrict__ tot, int* __restrict__ bbase,
    int* __restrict__ cursor) {
  int t = threadIdx.x;  // one wave of 64
  int v = (tot[t] + 7) & ~7;  // pad each bucket to multiple of 8 records
  int inc = v;
#pragma unroll
  for (int off = 1; off < 64; off <<= 1) {
    int x = __shfl_up(inc, off);
    if (t >= off) inc += x;
  }
  int base = inc - v;  // exclusive scan
  bbase[t] = base;
  cursor[t] = base;
}

// ---------- K4: scatter into bucket-contiguous 16 B records ----------

__global__ __launch_bounds__(256) void scatter_kernel(
    const int* __restrict__ rows, const int* __restrict__ cols,
    const float* __restrict__ mask, int nnz, int epb,
    int* __restrict__ cursor, int4* __restrict__ recs) {
  __shared__ int h[NBUCK];
  __shared__ int startS[NBUCK];
  if (threadIdx.x < NBUCK) h[threadIdx.x] = 0;
  __syncthreads();
  int lo = blockIdx.x * epb;
  int hi = min(lo + epb, nnz);
  for (int i = lo + threadIdx.x; i < hi; i += 256) {
    atomicAdd(&h[cols[i] >> 7], 1);
  }
  __syncthreads();
  if (threadIdx.x < NBUCK) {
    int c = h[threadIdx.x];
    startS[threadIdx.x] = c ? atomicAdd(&cursor[threadIdx.x], c) : 0;
    h[threadIdx.x] = 0;
  }
  __syncthreads();
  for (int i = lo + threadIdx.x; i < hi; i += 256) {
    int c = cols[i];
    int b = c >> 7;
    int rank = atomicAdd(&h[b], 1);
    int pos = startS[b] + rank;
    int4 rec;
    rec.x = (rows[i] << 16) | c;
    rec.y = i;
    rec.z = __float_as_int(mask[i]);
    rec.w = 0;
    recs[pos] = rec;
  }
}

// ---------- K5: sddmm with LDS col-slab ----------

__device__ __forceinline__ float dot8(const F4H8& a, const F4H8& b) {
  float s = 0.f;
#if __has_builtin(__builtin_amdgcn_fdot2)
#pragma unroll
  for (int j = 0; j < 4; ++j) s = __builtin_amdgcn_fdot2(a.h2[j], b.h2[j], s, false);
#else
#pragma unroll
  for (int j = 0; j < 8; ++j) s += (float)a.h[j] * (float)b.h[j];
#endif
  return s;
}

__device__ __forceinline__ float red16(float s) {
  s += __shfl_xor(s, 8);
  s += __shfl_xor(s, 4);
  s += __shfl_xor(s, 2);
  s += __shfl_xor(s, 1);
  return s;
}

__global__ __launch_bounds__(512) void sddmm_slab_kernel(
    const _Float16* __restrict__ m1,   // [M, 128] fp16
    const _Float16* __restrict__ m2t,  // [N, 128] fp16
    const int4* __restrict__ recs,
    const int* __restrict__ bbase,
    const int* __restrict__ tot,
    float* __restrict__ out) {
  __shared__ _Float16 slab[SLAB_COLS * KDIM];  // 32 KB
  int s = blockIdx.x / SUBS;
  int sub = blockIdx.x % SUBS;

  {  // stage contiguous 32 KB col-slab of m2t
    const float4* src = (const float4*)(m2t + (size_t)s * SLAB_COLS * KDIM);
    float4* dst = (float4*)slab;
#pragma unroll
    for (int i = 0; i < 4; ++i) {
      dst[threadIdx.x + i * 512] = src[threadIdx.x + i * 512];
    }
  }
  __syncthreads();

  int start = bbase[s];
  int cnt = tot[s];
  int hi0 = start + cnt;
  int per = ((cnt + SUBS - 1) / SUBS + 3) & ~3;
  int lo = start + sub * per;
  int hi = min(lo + per, hi0);

  int grp = threadIdx.x >> 4;  // 32 groups of 16 lanes
  int lane = threadIdx.x & 15;

  for (int g0 = lo + grp * 4; g0 < hi; g0 += 32 * 4) {
    if (g0 + 4 <= hi) {
      int4 r0 = recs[g0];
      int4 r1 = recs[g0 + 1];
      int4 r2 = recs[g0 + 2];
      int4 r3 = recs[g0 + 3];

      F4H8 a0, a1, a2, a3, b0, b1, b2, b3;
      a0.f4 = ((const float4*)(m1 + (size_t)((unsigned)r0.x >> 16) * KDIM))[lane];
      a1.f4 = ((const float4*)(m1 + (size_t)((unsigned)r1.x >> 16) * KDIM))[lane];
      a2.f4 = ((const float4*)(m1 + (size_t)((unsigned)r2.x >> 16) * KDIM))[lane];
      a3.f4 = ((const float4*)(m1 + (size_t)((unsigned)r3.x >> 16) * KDIM))[lane];
      b0.f4 = ((const float4*)(slab + (r0.x & (SLAB_COLS - 1)) * KDIM))[lane];
      b1.f4 = ((const float4*)(slab + (r1.x & (SLAB_COLS - 1)) * KDIM))[lane];
      b2.f4 = ((const float4*)(slab + (r2.x & (SLAB_COLS - 1)) * KDIM))[lane];
      b3.f4 = ((const float4*)(slab + (r3.x & (SLAB_COLS - 1)) * KDIM))[lane];

      float s0 = red16(dot8(a0, b0));
      float s1 = red16(dot8(a1, b1));
      float s2 = red16(dot8(a2, b2));
      float s3 = red16(dot8(a3, b3));

      if (lane == 0) {
        out[r0.y] = __int_as_float(r0.z) + s0;
        out[r1.y] = __int_as_float(r1.z) + s1;
        out[r2.y] = __int_as_float(r2.z) + s2;
        out[r3.y] = __int_as_float(r3.z) + s3;
      }
    } else {
      for (int g = g0; g < hi; ++g) {
        int4 r = recs[g];
        F4H8 a, b;
        a.f4 = ((const float4*)(m1 + (size_t)((unsigned)r.x >> 16) * KDIM))[lane];
        b.f4 = ((const float4*)(slab + (r.x & (SLAB_COLS - 1)) * KDIM))[lane];
        float sv = red16(dot8(a, b));
        if (lane == 0) out[r.y] = __int_as_float(r.z) + sv;
      }
    }
  }
}

// ---------- fallbacks ----------

__global__ __launch_bounds__(256) void convert_f16_kernel(
    const float* __restrict__ in, _Float16* __restrict__ out, int n) {
  int i = (blockIdx.x * 256 + threadIdx.x) * 8;
  if (i >= n) return;
  const float4* p = (const float4*)(in + i);
  float4 x0 = p[0];
  float4 x1 = p[1];
  F4H8 o;
  o.h[0] = (_Float16)x0.x; o.h[1] = (_Float16)x0.y;
  o.h[2] = (_Float16)x0.z; o.h[3] = (_Float16)x0.w;
  o.h[4] = (_Float16)x1.x; o.h[5] = (_Float16)x1.y;
  o.h[6] = (_Float16)x1.z; o.h[7] = (_Float16)x1.w;
  *(float4*)(out + i) = o.f4;
}

__global__ __launch_bounds__(256) void transpose_f16_kernel(
    const float* __restrict__ in, _Float16* __restrict__ out, int N) {
  __shared__ float tile[32][33];
  int bx = blockIdx.x * 32;
  int by = blockIdx.y * 32;
  int tx = threadIdx.x;
  int ty = threadIdx.y;
#pragma unroll
  for (int j = 0; j < 32; j += 8) {
    tile[ty + j][tx] = in[(size_t)(by + ty + j) * N + (bx + tx)];
  }
  __syncthreads();
#pragma unroll
  for (int j = 0; j < 32; j += 8) {
    out[(size_t)(bx + ty + j) * KDIM + (by + tx)] = (_Float16)tile[tx][ty + j];
  }
}

__global__ __launch_bounds__(256) void sddmm_f16_b4_kernel(
    const float* __restrict__ mask_vals, const int* __restrict__ rows,
    const int* __restrict__ cols, const _Float16* __restrict__ m1,
    const _Float16* __restrict__ m2t, float* __restrict__ out, int nnz) {
  int tid = blockIdx.x * 256 + threadIdx.x;
  int grp = tid >> 4;
  int lane = tid & 15;
  int g0 = grp * 4;
  if (g0 >= nnz) return;
  if (g0 + 4 <= nnz) {
    int4 r4 = *(const int4*)(rows + g0);
    int4 c4 = *(const int4*)(cols + g0);
    F4H8 a0, a1, a2, a3, b0, b1, b2, b3;
    a0.f4 = ((const float4*)(m1 + (size_t)r4.x * KDIM))[lane];
    a1.f4 = ((const float4*)(m1 + (size_t)r4.y * KDIM))[lane];
    a2.f4 = ((const float4*)(m1 + (size_t)r4.z * KDIM))[lane];
    a3.f4 = ((const float4*)(m1 + (size_t)r4.w * KDIM))[lane];
    b0.f4 = ((const float4*)(m2t + (size_t)c4.x * KDIM))[lane];
    b1.f4 = ((const float4*)(m2t + (size_t)c4.y * KDIM))[lane];
    b2.f4 = ((const float4*)(m2t + (size_t)c4.z * KDIM))[lane];
    b3.f4 = ((const float4*)(m2t + (size_t)c4.w * KDIM))[lane];
    float s0 = red16(dot8(a0, b0));
    float s1 = red16(dot8(a1, b1));
    float s2 = red16(dot8(a2, b2));
    float s3 = red16(dot8(a3, b3));
    if (lane == 0) {
      float4 mv = *(const float4*)(mask_vals + g0);
      float4 o = {mv.x + s0, mv.y + s1, mv.z + s2, mv.w + s3};
      *(float4*)(out + g0) = o;
    }
  } else {
    for (int g = g0; g < nnz; ++g) {
      F4H8 a, b;
      a.f4 = ((const float4*)(m1 + (size_t)rows[g] * KDIM))[lane];
      b.f4 = ((const float4*)(m2t + (size_t)cols[g] * KDIM))[lane];
      float sv = red16(dot8(a, b));
      if (lane == 0) out[g] = mask_vals[g] + sv;
    }
  }
}

__global__ __launch_bounds__(256) void sddmm16_strided_kernel(
    const float* __restrict__ mask_vals, const int* __restrict__ rows,
    const int* __restrict__ cols, const float* __restrict__ mat1,
    const float* __restrict__ mat2, float* __restrict__ out, int nnz, int N) {
  int tid = blockIdx.x * 256 + threadIdx.x;
  int g = tid >> 4;
  int lane = tid & 15;
  if (g >= nnz) return;
  int r = rows[g];
  int c = cols[g];
  const float* arow = mat1 + (size_t)r * KDIM;
  float s = 0.f;
#pragma unroll
  for (int j = 0; j < 8; ++j) {
    int k = lane + 16 * j;
    s += arow[k] * mat2[(size_t)k * N + c];
  }
  s = red16(s);
  if (lane == 0) out[g] = mask_vals[g] + s;
}

// ---------- launch ----------

extern "C" void kernel_launch(void* const* d_in, const int* in_sizes, int n_in,
                              void* d_out, int out_size, void* d_ws, size_t ws_size,
                              hipStream_t stream) {
  const float* mask_vals = (const float*)d_in[0];
  const int*   rows      = (const int*)d_in[1];
  const int*   cols      = (const int*)d_in[2];
  const float* mat1      = (const float*)d_in[3];
  const float* mat2      = (const float*)d_in[4];
  float*       out       = (float*)d_out;

  int nnz   = in_sizes[0];
  int m1_sz = in_sizes[3];        // M * 128
  int N     = in_sizes[4] / KDIM; // mat2 is [128, N]

  auto align256 = [](size_t x) { return (x + 255) & ~(size_t)255; };
  size_t off = 0;
  size_t o_m1h  = off; off = align256(off + (size_t)m1_sz * 2);
  size_t o_m2th = off; off = align256(off + (size_t)KDIM * N * 2);
  size_t cap    = (size_t)nnz + 8 * NBUCK + 64;
  size_t o_rec  = off; off = align256(off + cap * 16);
  size_t o_tot  = off; off = align256(off + NBUCK * 4);
  size_t o_bb   = off; off = align256(off + NBUCK * 4);
  size_t o_cur  = off; off = align256(off + NBUCK * 4);
  size_t need_full = off;
  size_t need_min  = align256((size_t)m1_sz * 2) + align256((size_t)KDIM * N * 2);

  char* ws = (char*)d_ws;

  if (ws_size >= need_full && N == NBUCK * SLAB_COLS && m1_sz % 2048 == 0) {
    _Float16* m1h  = (_Float16*)(ws + o_m1h);
    _Float16* m2th = (_Float16*)(ws + o_m2th);
    int4*     recs = (int4*)(ws + o_rec);
    int*      tot  = (int*)(ws + o_tot);
    int*      bb   = (int*)(ws + o_bb);
    int*      cur  = (int*)(ws + o_cur);

    int nconvblk  = (m1_sz / 8 + 255) / 256;
    int ntransblk = (N / 32) * (KDIM / 32);
    prep_kernel<<<nconvblk + ntransblk, 256, 0, stream>>>(
        mat1, m1h, m1_sz, mat2, m2th, N, tot, nconvblk);

    int epb = (nnz + NBLK - 1) / NBLK;
    hist_kernel<<<NBLK, 256, 0, stream>>>(cols, nnz, epb, tot);
    scan_kernel<<<1, 64, 0, stream>>>(tot, bb, cur);
    scatter_kernel<<<NBLK, 256, 0, stream>>>(rows, cols, mask_vals, nnz, epb,
                                             cur, recs);
    sddmm_slab_kernel<<<NBUCK * SUBS, 512, 0, stream>>>(m1h, m2th, recs, bb,
                                                        tot, out);
  } else if (ws_size >= need_min) {
    _Float16* m1h  = (_Float16*)ws;
    _Float16* m2th = m1h + m1_sz;
    convert_f16_kernel<<<(m1_sz / 8 + 255) / 256, 256, 0, stream>>>(mat1, m1h, m1_sz);
    dim3 tb(32, 8);
    dim3 tg(N / 32, KDIM / 32);
    transpose_f16_kernel<<<tg, tb, 0, stream>>>(mat2, m2th, N);
    int groups = (nnz + 3) / 4;
    int blocks = (groups * 16 + 255) / 256;
    sddmm_f16_b4_kernel<<<blocks, 256, 0, stream>>>(mask_vals, rows, cols, m1h,
                                                    m2th, out, nnz);
  } else {
    int blocks = ((size_t)nnz * 16 + 255) / 256;
    sddmm16_strided_kernel<<<blocks, 256, 0, stream>>>(mask_vals, rows, cols,
                                                       mat1, mat2, out, nnz, N);
  }
}

// Round 6
// 100.109 us; speedup vs baseline: 1.3212x; 1.3212x over previous
//
#include <hip/hip_runtime.h>
#include <hip/hip_fp16.h>

// SDDMM: out[n] = mask_vals[n] + dot(mat1[rows[n], :], mat2[:, cols[n]])
// NNZ = 1e6, M = N = 8192, K = 128, fp32 in/out. Indices int32 per harness.
//
// History:
// R1: fp32 working set 8 MB > 4 MiB/XCD L2 -> 277 MB fabric traffic, 80 us.
// R2: fp16 (4 MB, L2-resident per XCD) -> 63 us, latency-bound (MLP=2).
// R3: batch 4 nnz per 16-lane group (MLP=8) -> sddmm ~42 us. Measured
//     random-gather service: 4e6 x 128B lines / 42 us = ~5 lines/cyc/XCD
//     (~12 TB/s effective vs 34.5 TB/s streaming L2) -- the L2 random wall.
// R4/R5: col-slab counting sort + LDS slab halves gather lines but the sort
//     machinery (atomic contention on 64 counters, record materialization,
//     scattered out stores, 5-7 dispatches) costs 25-30 us vs ~15-20 saved.
//     Both regressed (122.6 / 132.3 vs R3's 100.8). Approach abandoned.
// R6: R3 structure, prep fused into ONE kernel (convert mat1 + transpose
//     mat2), 2 dispatches total. fp8 rejected: e4m3 rounding -> absmax ~4
//     vs 1.27 threshold. Deeper batching rejected: MLP already saturates
//     the CU VMEM queue; the wall is L2-side service rate.

#define KDIM 128

typedef _Float16 half2v __attribute__((ext_vector_type(2)));

union F4H8 {
  float4 f4;
  half2v h2[4];
  _Float16 h[8];
};

// ---------- K1: convert mat1 -> fp16, transpose+convert mat2 -> fp16 ----------

__global__ __launch_bounds__(256) void prep_kernel(
    const float* __restrict__ mat1, _Float16* __restrict__ m1h, int m1_sz,
    const float* __restrict__ mat2, _Float16* __restrict__ m2th, int N,
    int nconvblk) {
  __shared__ float tile[32][33];
  int blk = blockIdx.x;
  if (blk < nconvblk) {
    // mat1 [M,128] fp32 -> m1h fp16, same layout. 8 elems/thread.
    int i = (blk * 256 + threadIdx.x) * 8;
    if (i < m1_sz) {
      const float4* p = (const float4*)(mat1 + i);
      float4 x0 = p[0];
      float4 x1 = p[1];
      F4H8 o;
      o.h[0] = (_Float16)x0.x; o.h[1] = (_Float16)x0.y;
      o.h[2] = (_Float16)x0.z; o.h[3] = (_Float16)x0.w;
      o.h[4] = (_Float16)x1.x; o.h[5] = (_Float16)x1.y;
      o.h[6] = (_Float16)x1.z; o.h[7] = (_Float16)x1.w;
      *(float4*)(m1h + i) = o.f4;
    }
    return;
  }
  // mat2 [128, N] fp32 -> m2th [N, 128] fp16. 32x32 tiles via padded LDS.
  int u = blk - nconvblk;
  int nbx = N / 32;
  int bx = (u % nbx) * 32;  // N dim
  int by = (u / nbx) * 32;  // K dim
  int tx = threadIdx.x & 31;
  int ty = threadIdx.x >> 5;  // 0..7
#pragma unroll
  for (int j = 0; j < 32; j += 8) {
    tile[ty + j][tx] = mat2[(size_t)(by + ty + j) * N + (bx + tx)];
  }
  __syncthreads();
#pragma unroll
  for (int j = 0; j < 32; j += 8) {
    m2th[(size_t)(bx + ty + j) * KDIM + (by + tx)] = (_Float16)tile[tx][ty + j];
  }
}

// ---------- K2: sddmm, 16-lane group x 4 nnz (MLP=8) ----------

__device__ __forceinline__ float dot8(const F4H8& a, const F4H8& b) {
  float s = 0.f;
#if __has_builtin(__builtin_amdgcn_fdot2)
#pragma unroll
  for (int j = 0; j < 4; ++j) s = __builtin_amdgcn_fdot2(a.h2[j], b.h2[j], s, false);
#else
#pragma unroll
  for (int j = 0; j < 8; ++j) s += (float)a.h[j] * (float)b.h[j];
#endif
  return s;
}

__device__ __forceinline__ float red16(float s) {
  s += __shfl_xor(s, 8);
  s += __shfl_xor(s, 4);
  s += __shfl_xor(s, 2);
  s += __shfl_xor(s, 1);
  return s;
}

__global__ __launch_bounds__(256) void sddmm_f16_b4_kernel(
    const float* __restrict__ mask_vals, const int* __restrict__ rows,
    const int* __restrict__ cols, const _Float16* __restrict__ m1,
    const _Float16* __restrict__ m2t, float* __restrict__ out, int nnz) {
  int tid = blockIdx.x * 256 + threadIdx.x;
  int grp = tid >> 4;   // 16 lanes per group; group handles 4 nnz
  int lane = tid & 15;
  int g0 = grp * 4;
  if (g0 >= nnz) return;
  if (g0 + 4 <= nnz) {
    // Group-uniform broadcast index loads.
    int4 r4 = *(const int4*)(rows + g0);
    int4 c4 = *(const int4*)(cols + g0);

    // 8 independent 16B gathers in flight before any arithmetic.
    F4H8 a0, a1, a2, a3, b0, b1, b2, b3;
    a0.f4 = ((const float4*)(m1 + (size_t)r4.x * KDIM))[lane];
    a1.f4 = ((const float4*)(m1 + (size_t)r4.y * KDIM))[lane];
    a2.f4 = ((const float4*)(m1 + (size_t)r4.z * KDIM))[lane];
    a3.f4 = ((const float4*)(m1 + (size_t)r4.w * KDIM))[lane];
    b0.f4 = ((const float4*)(m2t + (size_t)c4.x * KDIM))[lane];
    b1.f4 = ((const float4*)(m2t + (size_t)c4.y * KDIM))[lane];
    b2.f4 = ((const float4*)(m2t + (size_t)c4.z * KDIM))[lane];
    b3.f4 = ((const float4*)(m2t + (size_t)c4.w * KDIM))[lane];

    float s0 = red16(dot8(a0, b0));
    float s1 = red16(dot8(a1, b1));
    float s2 = red16(dot8(a2, b2));
    float s3 = red16(dot8(a3, b3));

    if (lane == 0) {
      float4 mv = *(const float4*)(mask_vals + g0);
      float4 o = {mv.x + s0, mv.y + s1, mv.z + s2, mv.w + s3};
      *(float4*)(out + g0) = o;  // lanes 0/16/32/48 -> contiguous 64 B
    }
  } else {
    for (int g = g0; g < nnz; ++g) {
      F4H8 a, b;
      a.f4 = ((const float4*)(m1 + (size_t)rows[g] * KDIM))[lane];
      b.f4 = ((const float4*)(m2t + (size_t)cols[g] * KDIM))[lane];
      float sv = red16(dot8(a, b));
      if (lane == 0) out[g] = mask_vals[g] + sv;
    }
  }
}

// ---------- fallback: fp32 strided, no workspace needed ----------

__global__ __launch_bounds__(256) void sddmm16_strided_kernel(
    const float* __restrict__ mask_vals, const int* __restrict__ rows,
    const int* __restrict__ cols, const float* __restrict__ mat1,
    const float* __restrict__ mat2, float* __restrict__ out, int nnz, int N) {
  int tid = blockIdx.x * 256 + threadIdx.x;
  int g = tid >> 4;
  int lane = tid & 15;
  if (g >= nnz) return;
  int r = rows[g];
  int c = cols[g];
  const float* arow = mat1 + (size_t)r * KDIM;
  float s = 0.f;
#pragma unroll
  for (int j = 0; j < 8; ++j) {
    int k = lane + 16 * j;
    s += arow[k] * mat2[(size_t)k * N + c];
  }
  s = red16(s);
  if (lane == 0) out[g] = mask_vals[g] + s;
}

// ---------- launch ----------

extern "C" void kernel_launch(void* const* d_in, const int* in_sizes, int n_in,
                              void* d_out, int out_size, void* d_ws, size_t ws_size,
                              hipStream_t stream) {
  const float* mask_vals = (const float*)d_in[0];
  const int*   rows      = (const int*)d_in[1];
  const int*   cols      = (const int*)d_in[2];
  const float* mat1      = (const float*)d_in[3];
  const float* mat2      = (const float*)d_in[4];
  float*       out       = (float*)d_out;

  int nnz   = in_sizes[0];
  int m1_sz = in_sizes[3];        // M * 128
  int N     = in_sizes[4] / KDIM; // mat2 is [128, N]

  auto align256 = [](size_t x) { return (x + 255) & ~(size_t)255; };
  size_t need = align256((size_t)m1_sz * 2) + align256((size_t)KDIM * N * 2);

  if (ws_size >= need && (m1_sz % 2048) == 0 && (N % 32) == 0) {
    _Float16* m1h  = (_Float16*)d_ws;
    _Float16* m2th = (_Float16*)((char*)d_ws + align256((size_t)m1_sz * 2));

    int nconvblk  = (m1_sz / 8 + 255) / 256;
    int ntransblk = (N / 32) * (KDIM / 32);
    prep_kernel<<<nconvblk + ntransblk, 256, 0, stream>>>(
        mat1, m1h, m1_sz, mat2, m2th, N, nconvblk);

    int groups = (nnz + 3) / 4;
    int blocks = (groups * 16 + 255) / 256;
    sddmm_f16_b4_kernel<<<blocks, 256, 0, stream>>>(mask_vals, rows, cols,
                                                    m1h, m2th, out, nnz);
  } else {
    int blocks = (int)(((size_t)nnz * 16 + 255) / 256);
    sddmm16_strided_kernel<<<blocks, 256, 0, stream>>>(mask_vals, rows, cols,
                                                       mat1, mat2, out, nnz, N);
  }
}